// Round 2
// baseline (377.988 us; speedup 1.0000x reference)
//
#include <hip/hip_runtime.h>
#include <stdint.h>

// ---------- types / helpers ----------
typedef __attribute__((ext_vector_type(8))) short bf16x8;
typedef __attribute__((ext_vector_type(4))) float f32x4;

__device__ __forceinline__ unsigned short f2bf(float f){
  unsigned u = __float_as_uint(f);
  u += 0x7FFFu + ((u >> 16) & 1u);          // round-to-nearest-even
  return (unsigned short)(u >> 16);
}
__device__ __forceinline__ float bf2f(unsigned short s){
  return __uint_as_float(((unsigned)s) << 16);
}

// LDS tiles: [rows][64 bf16] = 128 B/row, XOR-swizzled (16B slot ^ row&7)
__device__ __forceinline__ int lds_off(int r, int b){
  return r * 128 + (b ^ ((r & 7) << 4));
}
// 128-col (256 B/row) variant for the adj tile
__device__ __forceinline__ int ldsP_off(int r, int b){
  return r * 256 + (b ^ ((r & 7) << 4));
}

// stage tile from bf16 global rows: ROWS x 64 elems at (row0, k0)
template<int ROWS, int NT>
__device__ __forceinline__ void stage_bf16(unsigned short* lds, const unsigned short* g,
                                           long row0, long stride, long k0, int tid){
#pragma unroll
  for (int c = tid; c < ROWS * 8; c += NT){
    int r = c >> 3, s = c & 7;
    uint4 v = *(const uint4*)(g + (row0 + r) * stride + k0 + s * 8);
    *(uint4*)((char*)lds + lds_off(r, s * 16)) = v;
  }
}

// stage tile from f32 global rows, converting to bf16
template<int ROWS, int NT>
__device__ __forceinline__ void stage_f32(unsigned short* lds, const float* g,
                                          long row0, long stride, long k0, int tid){
#pragma unroll
  for (int c = tid; c < ROWS * 8; c += NT){
    int r = c >> 3, s = c & 7;
    const float* src = g + (row0 + r) * stride + k0 + s * 8;
    float4 v0 = *(const float4*)(src);
    float4 v1 = *(const float4*)(src + 4);
    unsigned short t[8] = { f2bf(v0.x), f2bf(v0.y), f2bf(v0.z), f2bf(v0.w),
                            f2bf(v1.x), f2bf(v1.y), f2bf(v1.z), f2bf(v1.w) };
    *(uint4*)((char*)lds + lds_off(r, s * 16)) = *(const uint4*)t;
  }
}

// one BK=64 chunk of MFMAs for a 64x64 wave tile at (wm,wn)
__device__ __forceinline__ void mfma_chunk(const unsigned short* ldsA, const unsigned short* ldsB,
                                           int wm, int wn, int lane, f32x4 acc[4][4]){
  int r = lane & 15, gq = lane >> 4;
#pragma unroll
  for (int ks = 0; ks < 2; ++ks){
    bf16x8 a[4], b[4];
    int bb = ks * 64 + gq * 16;
#pragma unroll
    for (int m = 0; m < 4; ++m)
      a[m] = *(const bf16x8*)((const char*)ldsA + lds_off(wm * 64 + m * 16 + r, bb));
#pragma unroll
    for (int n = 0; n < 4; ++n)
      b[n] = *(const bf16x8*)((const char*)ldsB + lds_off(wn * 64 + n * 16 + r, bb));
#pragma unroll
    for (int m = 0; m < 4; ++m)
#pragma unroll
      for (int n = 0; n < 4; ++n)
        acc[m][n] = __builtin_amdgcn_mfma_f32_16x16x32_bf16(a[m], b[n], acc[m][n], 0, 0, 0);
  }
}

// ---------- prep: transpose weights to bf16, init score with bias ----------
__global__ __launch_bounds__(256) void k_prep(const float* Wm, const float* Wn,
    const float* Wr, const float* Wt, const float* Wrg, const float* Wlg, const float* bp,
    unsigned short* WT, unsigned short* WcatT, float* score){
  long id = (long)blockIdx.x * 256 + threadIdx.x;   // 0 .. 1024*512
  if (id < 1024L * 512){
    int n = (int)(id >> 9), k = (int)(id & 511);
    const float* W = (n < 256) ? Wm : ((n < 512) ? Wn : ((n < 768) ? Wr : Wt));
    WT[id] = f2bf(W[(long)k * 256 + (n & 255)]);
  }
  if (id < 256L * 512){
    int n = (int)(id >> 9), k = (int)(id & 511);
    WcatT[id] = f2bf(k < 256 ? Wrg[(long)k * 256 + n] : Wlg[(long)(k - 256) * 256 + n]);
  }
  if (id < 8192) score[id] = bp[0];
}

// ---------- pass A: [xm|xn|xwr|xl] = x @ [Wm|Wn|Wr|Wt]  (M=8192,K=512,N=1024) ----------
__global__ __launch_bounds__(256) void k_gemmA(const float* x, const unsigned short* WT,
    unsigned short* xm, unsigned short* xn, unsigned short* xwrT, unsigned short* xl){
  __shared__ unsigned short ldsA[128 * 64];
  __shared__ unsigned short ldsB[128 * 64];
  int tid = threadIdx.x, lane = tid & 63, w = tid >> 6;
  int wm = w >> 1, wn = w & 1;
  int bm = blockIdx.x, bn = blockIdx.y;       // 64 x 8
  f32x4 acc[4][4];
  f32x4 zero = {0.f, 0.f, 0.f, 0.f};
#pragma unroll
  for (int m = 0; m < 4; ++m)
#pragma unroll
    for (int n = 0; n < 4; ++n) acc[m][n] = zero;

  for (int k0 = 0; k0 < 512; k0 += 64){
    __syncthreads();
    stage_f32<128, 256>(ldsA, x, (long)bm * 128, 512, k0, tid);
    stage_bf16<128, 256>(ldsB, WT, (long)bn * 128, 512, k0, tid);
    __syncthreads();
    mfma_chunk(ldsA, ldsB, wm, wn, lane, acc);
  }
  int r = lane & 15, gq = lane >> 4;
  int i0 = bm * 128 + wm * 64;
  int n0 = bn * 128 + wn * 64;
#pragma unroll
  for (int m = 0; m < 4; ++m){
#pragma unroll
    for (int n = 0; n < 4; ++n){
      int ng = n0 + n * 16 + r;
      int sector = ng >> 8, nc = ng & 255;
      int ib = i0 + m * 16 + gq * 4;
      if (sector == 2){
        unsigned short p[4];
#pragma unroll
        for (int q = 0; q < 4; ++q) p[q] = f2bf(acc[m][n][q]);
        *(uint2*)(xwrT + (long)nc * 8192 + ib) =
            make_uint2((unsigned)p[0] | ((unsigned)p[1] << 16),
                       (unsigned)p[2] | ((unsigned)p[3] << 16));
      } else {
        unsigned short* dst = sector == 0 ? xm : (sector == 1 ? xn : xl);
#pragma unroll
        for (int q = 0; q < 4; ++q)
          dst[(long)(ib + q) * 256 + nc] = f2bf(acc[m][n][q]);
      }
    }
  }
}

// ---------- row norms of xm / xn ----------
__global__ __launch_bounds__(256) void k_norms(const unsigned short* xm, const unsigned short* xn,
                                               float* nm, float* nn){
  int w = threadIdx.x >> 6, lane = threadIdx.x & 63;
  int row = blockIdx.x * 4 + w;               // 0 .. 16384
  const unsigned short* src = (row < 8192) ? xm : xn;
  int rr = row & 8191;
  unsigned short v[4];
  *(uint2*)v = *(const uint2*)(src + (long)rr * 256 + lane * 4);
  float s = 0.f;
#pragma unroll
  for (int t = 0; t < 4; ++t){ float f = bf2f(v[t]); s += f * f; }
#pragma unroll
  for (int o = 32; o; o >>= 1) s += __shfl_xor(s, o);
  if (lane == 0) ((row < 8192) ? nm : nn)[rr] = s;
}

// ---------- fused pass B: adj tile + immediate adj@xwr accumulation ----------
// grid (64, NS); block 512 = 8 waves (2 x 4).
// Per bn-tile: phase1 adj = f(xm@xn^T) (wave tile 64x32), epilogue -> global adj
// + bf16 tile in swizzled LDS; phase2 acc2 += adjTile @ xwr (wave tile 64x64).
__global__ __launch_bounds__(512, 2) void k_adj_xr(
    const unsigned short* xm, const unsigned short* xn,
    const float* nm, const float* nn, const unsigned short* xwrT,
    float* adj, float* partial, int ntiles){
  __shared__ char smem[65536];
  unsigned short* ldsA  = (unsigned short*)smem;            // 16 KB [128][64]
  unsigned short* ldsB  = (unsigned short*)(smem + 16384);  // 16 KB [128][64]
  unsigned short* ldsB2 = (unsigned short*)smem;            // 32 KB alias [256][64]
  char*           ldsP  = smem + 32768;                     // 32 KB [128][128] bf16

  int tid = threadIdx.x, lane = tid & 63, w = tid >> 6;
  int r = lane & 15, gq = lane >> 4;
  int wm = w >> 2, wq = w & 3;
  int bm = blockIdx.x, sp = blockIdx.y;

  f32x4 zero = {0.f, 0.f, 0.f, 0.f};
  f32x4 acc2[4][4];
#pragma unroll
  for (int m = 0; m < 4; ++m)
#pragma unroll
    for (int n = 0; n < 4; ++n) acc2[m][n] = zero;

  float nmr[4][4];
#pragma unroll
  for (int m = 0; m < 4; ++m)
#pragma unroll
    for (int q = 0; q < 4; ++q)
      nmr[m][q] = nm[bm * 128 + wm * 64 + m * 16 + gq * 4 + q];

  for (int t = 0; t < ntiles; ++t){
    int bn = sp * ntiles + t;
    f32x4 acc1[4][2];
#pragma unroll
    for (int m = 0; m < 4; ++m)
#pragma unroll
      for (int n = 0; n < 2; ++n) acc1[m][n] = zero;

    // ---- phase 1: adj tile = xm[bm] @ xn[bn]^T, K=256 ----
    for (int k0 = 0; k0 < 256; k0 += 64){
      __syncthreads();
      stage_bf16<128, 512>(ldsA, xm, (long)bm * 128, 256, k0, tid);
      stage_bf16<128, 512>(ldsB, xn, (long)bn * 128, 256, k0, tid);
      __syncthreads();
#pragma unroll
      for (int ks = 0; ks < 2; ++ks){
        int bb = ks * 64 + gq * 16;
        bf16x8 a[4], b[2];
#pragma unroll
        for (int m = 0; m < 4; ++m)
          a[m] = *(const bf16x8*)((const char*)ldsA + lds_off(wm * 64 + m * 16 + r, bb));
#pragma unroll
        for (int n = 0; n < 2; ++n)
          b[n] = *(const bf16x8*)((const char*)ldsB + lds_off(wq * 32 + n * 16 + r, bb));
#pragma unroll
        for (int m = 0; m < 4; ++m)
#pragma unroll
          for (int n = 0; n < 2; ++n)
            acc1[m][n] = __builtin_amdgcn_mfma_f32_16x16x32_bf16(a[m], b[n], acc1[m][n], 0, 0, 0);
      }
    }

    // ---- epilogue: adj values -> global f32 + swizzled bf16 LDS tile ----
#pragma unroll
    for (int n = 0; n < 2; ++n){
      int jl = wq * 32 + n * 16 + r;
      long j = (long)bn * 128 + jl;
      float nnj = nn[j];
#pragma unroll
      for (int m = 0; m < 4; ++m){
#pragma unroll
        for (int q = 0; q < 4; ++q){
          int il = wm * 64 + m * 16 + gq * 4 + q;
          long i = (long)bm * 128 + il;
          float sq = nmr[m][q] + nnj - 2.f * acc1[m][n][q];
          float d = sqrtf(fmaxf(sq, 0.f)) * 0.5f;
          float v = (i == j) ? 1.f : __expf(-d) * (1.f / 128.f);
          adj[i * 8192 + j] = v;
          *(unsigned short*)(ldsP + ldsP_off(il, jl * 2)) = f2bf(v);
        }
      }
    }

    // ---- phase 2: acc2 += adjTile(128x128) @ xwr[bn-tile] (N=256) ----
    for (int k0 = 0; k0 < 128; k0 += 64){
      __syncthreads();   // P visible (k0=0); ldsB2/ldsA-B free of readers
      stage_bf16<256, 512>(ldsB2, xwrT, 0, 8192, (long)bn * 128 + k0, tid);
      __syncthreads();
#pragma unroll
      for (int ks = 0; ks < 2; ++ks){
        int kk = k0 + ks * 32;
        bf16x8 a[4], b[4];
#pragma unroll
        for (int m = 0; m < 4; ++m)
          a[m] = *(const bf16x8*)(ldsP + ldsP_off(wm * 64 + m * 16 + r, kk * 2 + gq * 16));
#pragma unroll
        for (int n = 0; n < 4; ++n)
          b[n] = *(const bf16x8*)((const char*)ldsB2 + lds_off(wq * 64 + n * 16 + r, ks * 64 + gq * 16));
#pragma unroll
        for (int m = 0; m < 4; ++m)
#pragma unroll
          for (int n = 0; n < 4; ++n)
            acc2[m][n] = __builtin_amdgcn_mfma_f32_16x16x32_bf16(a[m], b[n], acc2[m][n], 0, 0, 0);
      }
    }
  }

  // ---- write xr partial for this bn-chunk ----
  float* dst = partial + (long)sp * 8192 * 256;
#pragma unroll
  for (int m = 0; m < 4; ++m){
#pragma unroll
    for (int n = 0; n < 4; ++n){
      int c = wq * 64 + n * 16 + r;
#pragma unroll
      for (int q = 0; q < 4; ++q){
        long i = (long)bm * 128 + wm * 64 + m * 16 + gq * 4 + q;
        dst[i * 256 + c] = acc2[m][n][q];
      }
    }
  }
}

// ---------- reduce split partials -> xr (bf16) ----------
__global__ __launch_bounds__(256) void k_reduce_xr(const float* partial, unsigned short* xr, int S){
  long idx = ((long)blockIdx.x * 256 + threadIdx.x) * 4;   // 4 f32 each
  float4 a = *(const float4*)(partial + idx);
  for (int s = 1; s < S; ++s){
    const float4 b = *(const float4*)(partial + (long)s * 8192 * 256 + idx);
    a.x += b.x; a.y += b.y; a.z += b.z; a.w += b.w;
  }
  unsigned short p[4] = { f2bf(a.x), f2bf(a.y), f2bf(a.z), f2bf(a.w) };
  *(uint2*)(xr + idx) = make_uint2((unsigned)p[0] | ((unsigned)p[1] << 16),
                                   (unsigned)p[2] | ((unsigned)p[3] << 16));
}

// ---------- pass C: w = sigmoid([xr|xl]@[Wrg;Wlg] + b), feat, score ----------
__global__ __launch_bounds__(512) void k_gate(const unsigned short* xr, const unsigned short* xl,
    const unsigned short* WcatT, const float* brg, const float* blg,
    const float* Wp, float* score){
  __shared__ unsigned short ldsA[128 * 64];
  __shared__ unsigned short ldsB[256 * 64];
  int tid = threadIdx.x, lane = tid & 63, w = tid >> 6;
  int wm = w >> 2, wn = w & 3;                // 2 x 4 -> 128 x 256
  int bm = blockIdx.x;                        // 64 blocks
  f32x4 acc[4][4];
  f32x4 zero = {0.f, 0.f, 0.f, 0.f};
#pragma unroll
  for (int m = 0; m < 4; ++m)
#pragma unroll
    for (int n = 0; n < 4; ++n) acc[m][n] = zero;

  for (int k0 = 0; k0 < 512; k0 += 64){
    const unsigned short* A = (k0 < 256) ? xr : xl;
    __syncthreads();
    stage_bf16<128, 512>(ldsA, A, (long)bm * 128, 256, k0 & 255, tid);
    stage_bf16<256, 512>(ldsB, WcatT, 0, 512, k0, tid);
    __syncthreads();
    mfma_chunk(ldsA, ldsB, wm, wn, lane, acc);
  }
  int r = lane & 15, gq = lane >> 4;
#pragma unroll
  for (int m = 0; m < 4; ++m){
#pragma unroll
    for (int q = 0; q < 4; ++q){
      long i = (long)bm * 128 + wm * 64 + m * 16 + gq * 4 + q;
      float part = 0.f;
#pragma unroll
      for (int n = 0; n < 4; ++n){
        int c = wn * 64 + n * 16 + r;
        float arg = acc[m][n][q] + brg[c] + blg[c];
        float wv = 1.f / (1.f + __expf(-arg));
        float xrv = bf2f(xr[i * 256 + c]);
        float xlv = bf2f(xl[i * 256 + c]);
        float feat = (1.f - wv) * xrv + wv * xlv;
        part += feat * Wp[c];
      }
      part += __shfl_xor(part, 1);
      part += __shfl_xor(part, 2);
      part += __shfl_xor(part, 4);
      part += __shfl_xor(part, 8);
      if (r == 0) atomicAdd(score + i, part);
    }
  }
}

// ---------- host ----------
extern "C" void kernel_launch(void* const* d_in, const int* in_sizes, int n_in,
                              void* d_out, int out_size, void* d_ws, size_t ws_size,
                              hipStream_t stream){
  const float* x   = (const float*)d_in[0];
  const float* Wm  = (const float*)d_in[1];
  const float* Wn  = (const float*)d_in[2];
  const float* Wr  = (const float*)d_in[3];
  const float* Wt  = (const float*)d_in[4];
  const float* Wrg = (const float*)d_in[5];
  const float* brg = (const float*)d_in[6];
  const float* Wlg = (const float*)d_in[7];
  const float* blg = (const float*)d_in[8];
  const float* Wp  = (const float*)d_in[9];
  const float* bp  = (const float*)d_in[10];

  float* adj   = (float*)d_out;
  float* score = adj + 8192L * 8192;

  char* wsb = (char*)d_ws;
  unsigned short* xm    = (unsigned short*)(wsb);                 // 4 MB
  unsigned short* xn    = (unsigned short*)(wsb + (4L  << 20));   // 4 MB
  unsigned short* xwrT  = (unsigned short*)(wsb + (8L  << 20));   // 4 MB [256][8192]
  unsigned short* xl    = (unsigned short*)(wsb + (12L << 20));   // 4 MB
  unsigned short* xr    = (unsigned short*)(wsb + (16L << 20));   // 4 MB
  float*          nm    = (float*)         (wsb + (20L << 20));   // 32 KB
  float*          nn    = nm + 8192;                              // 32 KB
  unsigned short* WT    = (unsigned short*)(wsb + (21L << 20));   // 1 MB [1024][512]
  unsigned short* WcatT = (unsigned short*)(wsb + (22L << 20));   // 256 KB [256][512]
  float*          partial = (float*)(wsb + (23L << 20));          // NS * 8 MB

  int NS = 1;
  size_t base = 23L << 20;
  if      (ws_size >= base + 4 * (8L << 20)) NS = 4;
  else if (ws_size >= base + 2 * (8L << 20)) NS = 2;

  k_prep  <<<2048, 256, 0, stream>>>(Wm, Wn, Wr, Wt, Wrg, Wlg, bp, WT, WcatT, score);
  k_gemmA <<<dim3(64, 8), 256, 0, stream>>>(x, WT, xm, xn, xwrT, xl);
  k_norms <<<4096, 256, 0, stream>>>(xm, xn, nm, nn);
  k_adj_xr<<<dim3(64, NS), 512, 0, stream>>>(xm, xn, nm, nn, xwrT, adj, partial, 64 / NS);
  k_reduce_xr<<<2048, 256, 0, stream>>>(partial, xr, NS);
  k_gate  <<<64, 512, 0, stream>>>(xr, xl, WcatT, brg, blg, Wp, score);
}

// Round 3
// 345.173 us; speedup vs baseline: 1.0951x; 1.0951x over previous
//
#include <hip/hip_runtime.h>
#include <stdint.h>

// ---------- types / helpers ----------
typedef __attribute__((ext_vector_type(8))) short bf16x8;
typedef __attribute__((ext_vector_type(4))) float f32x4;

__device__ __forceinline__ unsigned short f2bf(float f){
  unsigned u = __float_as_uint(f);
  u += 0x7FFFu + ((u >> 16) & 1u);          // round-to-nearest-even
  return (unsigned short)(u >> 16);
}
__device__ __forceinline__ float bf2f(unsigned short s){
  return __uint_as_float(((unsigned)s) << 16);
}

// LDS tile layout: [rows][64 bf16] = 128 B/row; 16B slot s of row r holds
// global slot (s ^ (r&7)).  Reads use lds_off; async writes are linear with
// pre-swizzled global source (global_load_lds requires linear LDS dest).
__device__ __forceinline__ int lds_off(int r, int b){
  return r * 128 + (b ^ ((r & 7) << 4));
}

__device__ __forceinline__ void cp16(const unsigned short* g, unsigned short* l){
  __builtin_amdgcn_global_load_lds(
      (const __attribute__((address_space(1))) unsigned int*)g,
      (__attribute__((address_space(3))) unsigned int*)l, 16, 0, 0);
}

// async stage: ROWS x 64 bf16 tile from rows of g at (row0, k0), swizzled source
template<int ROWS, int NT>
__device__ __forceinline__ void stage_async(unsigned short* lds, const unsigned short* g,
                                            long row0, long stride, long k0, int tid){
#pragma unroll
  for (int c = tid; c < ROWS * 8; c += NT){
    int r = c >> 3, s = c & 7;
    int ss = s ^ (r & 7);
    cp16(g + (row0 + r) * stride + k0 + ss * 8, lds + (long)(c & ~63) * 8);
  }
}

// register-path stage from f32 global rows, converting to bf16 (fallback)
template<int ROWS, int NT>
__device__ __forceinline__ void stage_f32(unsigned short* lds, const float* g,
                                          long row0, long stride, long k0, int tid){
#pragma unroll
  for (int c = tid; c < ROWS * 8; c += NT){
    int r = c >> 3, s = c & 7;
    const float* src = g + (row0 + r) * stride + k0 + s * 8;
    float4 v0 = *(const float4*)(src);
    float4 v1 = *(const float4*)(src + 4);
    unsigned short t[8] = { f2bf(v0.x), f2bf(v0.y), f2bf(v0.z), f2bf(v0.w),
                            f2bf(v1.x), f2bf(v1.y), f2bf(v1.z), f2bf(v1.w) };
    *(uint4*)((char*)lds + lds_off(r, s * 16)) = *(const uint4*)t;
  }
}

// XCD-aware bijective swizzle (nwg % 8 == 0 in all uses)
__device__ __forceinline__ int xcd_swz(int bid, int nwg){
  int q = nwg >> 3;
  return (bid & 7) * q + (bid >> 3);
}

// ---------- prep: transpose weights to bf16, init score with bias ----------
__global__ __launch_bounds__(256) void k_prep(const float* Wm, const float* Wn,
    const float* Wr, const float* Wt, const float* Wrg, const float* Wlg, const float* bp,
    unsigned short* WT, unsigned short* WcatT, float* score){
  long id = (long)blockIdx.x * 256 + threadIdx.x;   // 0 .. 1024*512
  if (id < 1024L * 512){
    int n = (int)(id >> 9), k = (int)(id & 511);
    const float* W = (n < 256) ? Wm : ((n < 512) ? Wn : ((n < 768) ? Wr : Wt));
    WT[id] = f2bf(W[(long)k * 256 + (n & 255)]);
  }
  if (id < 256L * 512){
    int n = (int)(id >> 9), k = (int)(id & 511);
    WcatT[id] = f2bf(k < 256 ? Wrg[(long)k * 256 + n] : Wlg[(long)(k - 256) * 256 + n]);
  }
  if (id < 8192) score[id] = bp[0];
}

// ---------- convert x -> bf16 ----------
__global__ __launch_bounds__(256) void k_convx(const float* x, unsigned short* xbf){
  long id = ((long)blockIdx.x * 256 + threadIdx.x) * 8;
  float4 v0 = *(const float4*)(x + id);
  float4 v1 = *(const float4*)(x + id + 4);
  unsigned short t[8] = { f2bf(v0.x), f2bf(v0.y), f2bf(v0.z), f2bf(v0.w),
                          f2bf(v1.x), f2bf(v1.y), f2bf(v1.z), f2bf(v1.w) };
  *(uint4*)(xbf + id) = *(const uint4*)t;
}

// ---------- pass A: [xm|xn|xwr|xl] = x @ [Wm|Wn|Wr|Wt]  (M=8192,K=512,N=1024) ----------
__global__ __launch_bounds__(256, 3) void k_gemmA(const unsigned short* xbf, const unsigned short* WT,
    unsigned short* xm, unsigned short* xn, unsigned short* xwrT, unsigned short* xl){
  __shared__ unsigned short ldsA[128 * 64];
  __shared__ unsigned short ldsB[128 * 64];
  int tid = threadIdx.x, lane = tid & 63, w = tid >> 6;
  int r = lane & 15, gq = lane >> 4;
  int wi = w >> 1, wc = w & 1;
  int swz = xcd_swz(blockIdx.x, 512);
  int bm = swz & 63, bn = swz >> 6;           // 64 x 8

  f32x4 acc[4][4];
  f32x4 zero = {0.f, 0.f, 0.f, 0.f};
#pragma unroll
  for (int m = 0; m < 4; ++m)
#pragma unroll
    for (int n = 0; n < 4; ++n) acc[m][n] = zero;

  for (int k0 = 0; k0 < 512; k0 += 64){
    __syncthreads();
    stage_async<128, 256>(ldsA, xbf, (long)bm * 128, 512, k0, tid);
    stage_async<128, 256>(ldsB, WT, (long)bn * 128, 512, k0, tid);
    __syncthreads();
#pragma unroll
    for (int ks = 0; ks < 2; ++ks){
      int bb = ks * 64 + gq * 16;
      bf16x8 a[4], b[4];
#pragma unroll
      for (int m = 0; m < 4; ++m)
        a[m] = *(const bf16x8*)((const char*)ldsA + lds_off(wi * 64 + m * 16 + r, bb));
#pragma unroll
      for (int n = 0; n < 4; ++n)
        b[n] = *(const bf16x8*)((const char*)ldsB + lds_off(wc * 64 + n * 16 + r, bb));
      // swapped: row-dim = WT index (n), col-dim = x row (i)
#pragma unroll
      for (int m = 0; m < 4; ++m)
#pragma unroll
        for (int n = 0; n < 4; ++n)
          acc[m][n] = __builtin_amdgcn_mfma_f32_16x16x32_bf16(b[n], a[m], acc[m][n], 0, 0, 0);
    }
  }
#pragma unroll
  for (int m = 0; m < 4; ++m){
    int i = bm * 128 + wi * 64 + m * 16 + r;
#pragma unroll
    for (int n = 0; n < 4; ++n){
      int ng = bn * 128 + wc * 64 + n * 16 + gq * 4;
      int sector = ng >> 8, nc = ng & 255;
      unsigned short p[4] = { f2bf(acc[m][n][0]), f2bf(acc[m][n][1]),
                              f2bf(acc[m][n][2]), f2bf(acc[m][n][3]) };
      if (sector == 2){
#pragma unroll
        for (int q = 0; q < 4; ++q) xwrT[(long)(nc + q) * 8192 + i] = p[q];
      } else {
        unsigned short* dst = sector == 0 ? xm : (sector == 1 ? xn : xl);
        *(uint2*)(dst + (long)i * 256 + nc) = *(const uint2*)p;
      }
    }
  }
}

// ---------- row norms of xm / xn ----------
__global__ __launch_bounds__(256) void k_norms(const unsigned short* xm, const unsigned short* xn,
                                               float* nm, float* nn){
  int w = threadIdx.x >> 6, lane = threadIdx.x & 63;
  int row = blockIdx.x * 4 + w;               // 0 .. 16384
  const unsigned short* src = (row < 8192) ? xm : xn;
  int rr = row & 8191;
  unsigned short v[4];
  *(uint2*)v = *(const uint2*)(src + (long)rr * 256 + lane * 4);
  float s = 0.f;
#pragma unroll
  for (int t = 0; t < 4; ++t){ float f = bf2f(v[t]); s += f * f; }
#pragma unroll
  for (int o = 32; o; o >>= 1) s += __shfl_xor(s, o);
  if (lane == 0) ((row < 8192) ? nm : nn)[rr] = s;
}

// ---------- pass B1: adj = f(xm @ xn^T)  (M=N=8192, K=256) ----------
template<bool WRITE_BF>
__global__ __launch_bounds__(256, 3) void k_adj(const unsigned short* xm, const unsigned short* xn,
    const float* nm, const float* nn, float* adj, unsigned short* adjbf){
  __shared__ unsigned short ldsA[128 * 64];
  __shared__ unsigned short ldsB[128 * 64];
  int tid = threadIdx.x, lane = tid & 63, w = tid >> 6;
  int r = lane & 15, gq = lane >> 4;
  int wi = w >> 1, wj = w & 1;
  int swz = xcd_swz(blockIdx.x, 4096);
  int bm = swz & 63, bn = swz >> 6;           // 64 x 64

  f32x4 acc1[4][4];
  f32x4 zero = {0.f, 0.f, 0.f, 0.f};
#pragma unroll
  for (int m = 0; m < 4; ++m)
#pragma unroll
    for (int n = 0; n < 4; ++n) acc1[m][n] = zero;

  for (int k0 = 0; k0 < 256; k0 += 64){
    __syncthreads();
    stage_async<128, 256>(ldsA, xm, (long)bm * 128, 256, k0, tid);
    stage_async<128, 256>(ldsB, xn, (long)bn * 128, 256, k0, tid);
    __syncthreads();
#pragma unroll
    for (int ks = 0; ks < 2; ++ks){
      int bb = ks * 64 + gq * 16;
      bf16x8 a[4], b[4];
#pragma unroll
      for (int m = 0; m < 4; ++m)
        a[m] = *(const bf16x8*)((const char*)ldsA + lds_off(wi * 64 + m * 16 + r, bb));
#pragma unroll
      for (int n = 0; n < 4; ++n)
        b[n] = *(const bf16x8*)((const char*)ldsB + lds_off(wj * 64 + n * 16 + r, bb));
      // swapped: row-dim (gq*4+q) = xn index j, col-dim (r) = xm index i
#pragma unroll
      for (int m = 0; m < 4; ++m)
#pragma unroll
        for (int n = 0; n < 4; ++n)
          acc1[m][n] = __builtin_amdgcn_mfma_f32_16x16x32_bf16(b[n], a[m], acc1[m][n], 0, 0, 0);
    }
  }
#pragma unroll
  for (int m = 0; m < 4; ++m){
    int i = bm * 128 + wi * 64 + m * 16 + r;
    float nmi = nm[i];
    long ibase = (long)i * 8192;
#pragma unroll
    for (int n = 0; n < 4; ++n){
      int jb = bn * 128 + wj * 64 + n * 16 + gq * 4;
      float4 nn4 = *(const float4*)(nn + jb);
      float v[4];
      const float nnq[4] = { nn4.x, nn4.y, nn4.z, nn4.w };
#pragma unroll
      for (int q = 0; q < 4; ++q){
        float sq = nmi + nnq[q] - 2.f * acc1[m][n][q];
        float d = sqrtf(fmaxf(sq, 0.f)) * 0.5f;
        v[q] = (i == jb + q) ? 1.f : __expf(-d) * (1.f / 128.f);
      }
      *(float4*)(adj + ibase + jb) = make_float4(v[0], v[1], v[2], v[3]);
      if (WRITE_BF){
        unsigned short p[4] = { f2bf(v[0]), f2bf(v[1]), f2bf(v[2]), f2bf(v[3]) };
        *(uint2*)(adjbf + ibase + jb) = *(const uint2*)p;
      }
    }
  }
}

// ---------- pass B2: partial = adj @ xwr  (M=8192, K split, N=256) ----------
template<bool ABF>
__global__ __launch_bounds__(512, 2) void k_xr(const float* adj, const unsigned short* adjbf,
    const unsigned short* xwrT, float* partial, int klen, int nblk){
  __shared__ unsigned short ldsA[128 * 64];
  __shared__ unsigned short ldsB[256 * 64];
  int tid = threadIdx.x, lane = tid & 63, w = tid >> 6;
  int r = lane & 15, gq = lane >> 4;
  int wi = w >> 2, wc = w & 3;                // 2 x 4 -> 128 x 256
  int swz = xcd_swz(blockIdx.x, nblk);
  int bm = swz & 63, sp = swz >> 6;
  long j0 = (long)sp * klen;

  f32x4 acc[4][4];
  f32x4 zero = {0.f, 0.f, 0.f, 0.f};
#pragma unroll
  for (int m = 0; m < 4; ++m)
#pragma unroll
    for (int n = 0; n < 4; ++n) acc[m][n] = zero;

  for (int k0 = 0; k0 < klen; k0 += 64){
    __syncthreads();
    if (ABF) stage_async<128, 512>(ldsA, adjbf, (long)bm * 128, 8192, j0 + k0, tid);
    else     stage_f32  <128, 512>(ldsA, adj,   (long)bm * 128, 8192, j0 + k0, tid);
    stage_async<256, 512>(ldsB, xwrT, 0, 8192, j0 + k0, tid);
    __syncthreads();
#pragma unroll
    for (int ks = 0; ks < 2; ++ks){
      int bb = ks * 64 + gq * 16;
      bf16x8 a[4], b[4];
#pragma unroll
      for (int m = 0; m < 4; ++m)
        a[m] = *(const bf16x8*)((const char*)ldsA + lds_off(wi * 64 + m * 16 + r, bb));
#pragma unroll
      for (int n = 0; n < 4; ++n)
        b[n] = *(const bf16x8*)((const char*)ldsB + lds_off(wc * 64 + n * 16 + r, bb));
      // swapped: row-dim = xwrT index c, col-dim = adj row i
#pragma unroll
      for (int m = 0; m < 4; ++m)
#pragma unroll
        for (int n = 0; n < 4; ++n)
          acc[m][n] = __builtin_amdgcn_mfma_f32_16x16x32_bf16(b[n], a[m], acc[m][n], 0, 0, 0);
    }
  }
  float* dst = partial + (long)sp * 8192 * 256;
#pragma unroll
  for (int m = 0; m < 4; ++m){
    int i = bm * 128 + wi * 64 + m * 16 + r;
#pragma unroll
    for (int n = 0; n < 4; ++n){
      int cb = wc * 64 + n * 16 + gq * 4;
      *(f32x4*)(dst + (long)i * 256 + cb) = acc[m][n];
    }
  }
}

// ---------- reduce split partials -> xr (bf16) ----------
__global__ __launch_bounds__(256) void k_reduce_xr(const float* partial, unsigned short* xr, int S){
  long idx = ((long)blockIdx.x * 256 + threadIdx.x) * 4;
  float4 a = *(const float4*)(partial + idx);
  for (int s = 1; s < S; ++s){
    const float4 b = *(const float4*)(partial + (long)s * 8192 * 256 + idx);
    a.x += b.x; a.y += b.y; a.z += b.z; a.w += b.w;
  }
  unsigned short p[4] = { f2bf(a.x), f2bf(a.y), f2bf(a.z), f2bf(a.w) };
  *(uint2*)(xr + idx) = make_uint2((unsigned)p[0] | ((unsigned)p[1] << 16),
                                   (unsigned)p[2] | ((unsigned)p[3] << 16));
}

// ---------- pass C: w = sigmoid([xr|xl]@[Wrg;Wlg] + b), feat, score ----------
__global__ __launch_bounds__(512, 2) void k_gate(const unsigned short* xr, const unsigned short* xl,
    const unsigned short* WcatT, const float* brg, const float* blg,
    const float* Wp, float* score){
  __shared__ unsigned short ldsA[128 * 64];
  __shared__ unsigned short ldsB[256 * 64];
  int tid = threadIdx.x, lane = tid & 63, w = tid >> 6;
  int r = lane & 15, gq = lane >> 4;
  int wi = w >> 2, wc = w & 3;                // 2 x 4 -> 128 x 256
  int bm = blockIdx.x;

  f32x4 acc[4][4];
  f32x4 zero = {0.f, 0.f, 0.f, 0.f};
#pragma unroll
  for (int m = 0; m < 4; ++m)
#pragma unroll
    for (int n = 0; n < 4; ++n) acc[m][n] = zero;

  for (int k0 = 0; k0 < 512; k0 += 64){
    const unsigned short* A = (k0 < 256) ? xr : xl;
    __syncthreads();
    stage_async<128, 512>(ldsA, A, (long)bm * 128, 256, k0 & 255, tid);
    stage_async<256, 512>(ldsB, WcatT, 0, 512, k0, tid);
    __syncthreads();
#pragma unroll
    for (int ks = 0; ks < 2; ++ks){
      int bb = ks * 64 + gq * 16;
      bf16x8 a[4], b[4];
#pragma unroll
      for (int m = 0; m < 4; ++m)
        a[m] = *(const bf16x8*)((const char*)ldsA + lds_off(wi * 64 + m * 16 + r, bb));
#pragma unroll
      for (int n = 0; n < 4; ++n)
        b[n] = *(const bf16x8*)((const char*)ldsB + lds_off(wc * 64 + n * 16 + r, bb));
#pragma unroll
      for (int m = 0; m < 4; ++m)
#pragma unroll
        for (int n = 0; n < 4; ++n)
          acc[m][n] = __builtin_amdgcn_mfma_f32_16x16x32_bf16(b[n], a[m], acc[m][n], 0, 0, 0);
    }
  }
#pragma unroll
  for (int m = 0; m < 4; ++m){
    int i = bm * 128 + wi * 64 + m * 16 + r;
    float part = 0.f;
#pragma unroll
    for (int n = 0; n < 4; ++n){
      int cb = wc * 64 + n * 16 + gq * 4;
      float4 b4  = *(const float4*)(brg + cb);
      float4 l4  = *(const float4*)(blg + cb);
      float4 wp4 = *(const float4*)(Wp + cb);
      unsigned short xr4[4], xl4[4];
      *(uint2*)xr4 = *(const uint2*)(xr + (long)i * 256 + cb);
      *(uint2*)xl4 = *(const uint2*)(xl + (long)i * 256 + cb);
      const float bq[4] = { b4.x, b4.y, b4.z, b4.w };
      const float lq[4] = { l4.x, l4.y, l4.z, l4.w };
      const float pq[4] = { wp4.x, wp4.y, wp4.z, wp4.w };
#pragma unroll
      for (int q = 0; q < 4; ++q){
        float arg = acc[m][n][q] + bq[q] + lq[q];
        float wv = 1.f / (1.f + __expf(-arg));
        float feat = (1.f - wv) * bf2f(xr4[q]) + wv * bf2f(xl4[q]);
        part += feat * pq[q];
      }
    }
    part += __shfl_xor(part, 16);
    part += __shfl_xor(part, 32);
    if (gq == 0) atomicAdd(score + i, part);
  }
}

// ---------- host ----------
extern "C" void kernel_launch(void* const* d_in, const int* in_sizes, int n_in,
                              void* d_out, int out_size, void* d_ws, size_t ws_size,
                              hipStream_t stream){
  const float* x   = (const float*)d_in[0];
  const float* Wm  = (const float*)d_in[1];
  const float* Wn  = (const float*)d_in[2];
  const float* Wr  = (const float*)d_in[3];
  const float* Wt  = (const float*)d_in[4];
  const float* Wrg = (const float*)d_in[5];
  const float* brg = (const float*)d_in[6];
  const float* Wlg = (const float*)d_in[7];
  const float* blg = (const float*)d_in[8];
  const float* Wp  = (const float*)d_in[9];
  const float* bp  = (const float*)d_in[10];

  float* adj   = (float*)d_out;
  float* score = adj + 8192L * 8192;

  char* wsb = (char*)d_ws;
  unsigned short* xm    = (unsigned short*)(wsb);                 // 4 MB
  unsigned short* xn    = (unsigned short*)(wsb + (4L  << 20));   // 4 MB
  unsigned short* xwrT  = (unsigned short*)(wsb + (8L  << 20));   // 4 MB [256][8192]
  unsigned short* xl    = (unsigned short*)(wsb + (12L << 20));   // 4 MB
  unsigned short* xr    = (unsigned short*)(wsb + (16L << 20));   // 4 MB
  float*          nm    = (float*)         (wsb + (20L << 20));   // 32 KB
  float*          nn    = nm + 8192;                              // 32 KB
  unsigned short* WT    = (unsigned short*)(wsb + (21L << 20));   // 1 MB [1024][512]
  unsigned short* WcatT = (unsigned short*)(wsb + (22L << 20));   // 256 KB [256][512]
  unsigned short* xbf   = (unsigned short*)(wsb + (23L << 20));   // 8 MB [8192][512]
  float*          partial = (float*)(wsb + (31L << 20));          // NS * 8 MB

  int NS = 1;
  size_t base = 31L << 20;
  if      (ws_size >= base + 4 * (8L << 20)) NS = 4;
  else if (ws_size >= base + 2 * (8L << 20)) NS = 2;
  size_t adjbf_off = base + (size_t)NS * (8L << 20);
  bool use_bf = ws_size >= adjbf_off + (128L << 20);
  unsigned short* adjbf = (unsigned short*)(wsb + adjbf_off);

  k_prep  <<<2048, 256, 0, stream>>>(Wm, Wn, Wr, Wt, Wrg, Wlg, bp, WT, WcatT, score);
  k_convx <<<2048, 256, 0, stream>>>(x, xbf);
  k_gemmA <<<512, 256, 0, stream>>>(xbf, WT, xm, xn, xwrT, xl);
  k_norms <<<4096, 256, 0, stream>>>(xm, xn, nm, nn);
  if (use_bf){
    k_adj<true>  <<<4096, 256, 0, stream>>>(xm, xn, nm, nn, adj, adjbf);
    k_xr<true>   <<<64 * NS, 512, 0, stream>>>(adj, adjbf, xwrT, partial, 8192 / NS, 64 * NS);
  } else {
    k_adj<false> <<<4096, 256, 0, stream>>>(xm, xn, nm, nn, adj, adjbf);
    k_xr<false>  <<<64 * NS, 512, 0, stream>>>(adj, adjbf, xwrT, partial, 8192 / NS, 64 * NS);
  }
  k_reduce_xr<<<2048, 256, 0, stream>>>(partial, xr, NS);
  k_gate  <<<64, 512, 0, stream>>>(xr, xl, WcatT, brg, blg, Wp, score);
}

// Round 4
// 339.614 us; speedup vs baseline: 1.1130x; 1.0164x over previous
//
#include <hip/hip_runtime.h>
#include <stdint.h>

// ---------- types / helpers ----------
typedef __attribute__((ext_vector_type(8))) short bf16x8;
typedef __attribute__((ext_vector_type(4))) float f32x4;

__device__ __forceinline__ unsigned short f2bf(float f){
  unsigned u = __float_as_uint(f);
  u += 0x7FFFu + ((u >> 16) & 1u);          // round-to-nearest-even
  return (unsigned short)(u >> 16);
}
__device__ __forceinline__ float bf2f(unsigned short s){
  return __uint_as_float(((unsigned)s) << 16);
}

// LDS tile layout: [rows][64 bf16] = 128 B/row; 16B slot s of row r holds
// global slot (s ^ (r&7)).  Reads use lds_off; async writes are linear with
// pre-swizzled global source (global_load_lds requires linear LDS dest).
__device__ __forceinline__ int lds_off(int r, int b){
  return r * 128 + (b ^ ((r & 7) << 4));
}

__device__ __forceinline__ void cp16(const unsigned short* g, unsigned short* l){
  __builtin_amdgcn_global_load_lds(
      (const __attribute__((address_space(1))) unsigned int*)g,
      (__attribute__((address_space(3))) unsigned int*)l, 16, 0, 0);
}

// async stage: ROWS x 64 bf16 tile from rows of g at (row0, k0), swizzled source
template<int ROWS, int NT>
__device__ __forceinline__ void stage_async(unsigned short* lds, const unsigned short* g,
                                            long row0, long stride, long k0, int tid){
#pragma unroll
  for (int c = tid; c < ROWS * 8; c += NT){
    int r = c >> 3, s = c & 7;
    int ss = s ^ (r & 7);
    cp16(g + (row0 + r) * stride + k0 + ss * 8, lds + (long)(c & ~63) * 8);
  }
}

// register-path stage from f32 global rows, converting to bf16 (fallback)
template<int ROWS, int NT>
__device__ __forceinline__ void stage_f32(unsigned short* lds, const float* g,
                                          long row0, long stride, long k0, int tid){
#pragma unroll
  for (int c = tid; c < ROWS * 8; c += NT){
    int r = c >> 3, s = c & 7;
    const float* src = g + (row0 + r) * stride + k0 + s * 8;
    float4 v0 = *(const float4*)(src);
    float4 v1 = *(const float4*)(src + 4);
    unsigned short t[8] = { f2bf(v0.x), f2bf(v0.y), f2bf(v0.z), f2bf(v0.w),
                            f2bf(v1.x), f2bf(v1.y), f2bf(v1.z), f2bf(v1.w) };
    *(uint4*)((char*)lds + lds_off(r, s * 16)) = *(const uint4*)t;
  }
}

// XCD-aware bijective swizzle (nwg % 8 == 0 in all uses)
__device__ __forceinline__ int xcd_swz(int bid, int nwg){
  int q = nwg >> 3;
  return (bid & 7) * q + (bid >> 3);
}

// ---------- prep: weights -> bf16 transposed, x -> bf16, init score ----------
__global__ __launch_bounds__(256) void k_prep(const float* x, const float* Wm, const float* Wn,
    const float* Wr, const float* Wt, const float* Wrg, const float* Wlg, const float* bp,
    unsigned short* WT, unsigned short* WcatT, unsigned short* xbf, float* score){
  long id = (long)blockIdx.x * 256 + threadIdx.x;   // 0 .. 524288
  if (id < 1024L * 512){
    int n = (int)(id >> 9), k = (int)(id & 511);
    const float* W = (n < 256) ? Wm : ((n < 512) ? Wn : ((n < 768) ? Wr : Wt));
    WT[id] = f2bf(W[(long)k * 256 + (n & 255)]);
  }
  if (id < 256L * 512){
    int n = (int)(id >> 9), k = (int)(id & 511);
    WcatT[id] = f2bf(k < 256 ? Wrg[(long)k * 256 + n] : Wlg[(long)(k - 256) * 256 + n]);
  }
  if (id < 8192) score[id] = bp[0];
  // x -> bf16 (8 per thread, 4M total)
  long xe = id * 8;
  float4 v0 = *(const float4*)(x + xe);
  float4 v1 = *(const float4*)(x + xe + 4);
  unsigned short t[8] = { f2bf(v0.x), f2bf(v0.y), f2bf(v0.z), f2bf(v0.w),
                          f2bf(v1.x), f2bf(v1.y), f2bf(v1.z), f2bf(v1.w) };
  *(uint4*)(xbf + xe) = *(const uint4*)t;
}

// ---------- pass A: [xm|xn|xwr|xl] = x @ [Wm|Wn|Wr|Wt]  (M=8192,K=512,N=1024) ----------
__global__ __launch_bounds__(256, 3) void k_gemmA(const unsigned short* xbf, const unsigned short* WT,
    unsigned short* xm, unsigned short* xn, unsigned short* xwrT, unsigned short* xl){
  __shared__ unsigned short ldsA[128 * 64];
  __shared__ unsigned short ldsB[128 * 64];
  int tid = threadIdx.x, lane = tid & 63, w = tid >> 6;
  int r = lane & 15, gq = lane >> 4;
  int wi = w >> 1, wc = w & 1;
  int swz = xcd_swz(blockIdx.x, 512);
  int bm = swz & 63, bn = swz >> 6;           // 64 x 8

  f32x4 acc[4][4];
  f32x4 zero = {0.f, 0.f, 0.f, 0.f};
#pragma unroll
  for (int m = 0; m < 4; ++m)
#pragma unroll
    for (int n = 0; n < 4; ++n) acc[m][n] = zero;

  for (int k0 = 0; k0 < 512; k0 += 64){
    __syncthreads();
    stage_async<128, 256>(ldsA, xbf, (long)bm * 128, 512, k0, tid);
    stage_async<128, 256>(ldsB, WT, (long)bn * 128, 512, k0, tid);
    __syncthreads();
#pragma unroll
    for (int ks = 0; ks < 2; ++ks){
      int bb = ks * 64 + gq * 16;
      bf16x8 a[4], b[4];
#pragma unroll
      for (int m = 0; m < 4; ++m)
        a[m] = *(const bf16x8*)((const char*)ldsA + lds_off(wi * 64 + m * 16 + r, bb));
#pragma unroll
      for (int n = 0; n < 4; ++n)
        b[n] = *(const bf16x8*)((const char*)ldsB + lds_off(wc * 64 + n * 16 + r, bb));
      // swapped: row-dim = WT index (n), col-dim = x row (i)
#pragma unroll
      for (int m = 0; m < 4; ++m)
#pragma unroll
        for (int n = 0; n < 4; ++n)
          acc[m][n] = __builtin_amdgcn_mfma_f32_16x16x32_bf16(b[n], a[m], acc[m][n], 0, 0, 0);
    }
  }
#pragma unroll
  for (int m = 0; m < 4; ++m){
    int i = bm * 128 + wi * 64 + m * 16 + r;
#pragma unroll
    for (int n = 0; n < 4; ++n){
      int ng = bn * 128 + wc * 64 + n * 16 + gq * 4;
      int sector = ng >> 8, nc = ng & 255;
      unsigned short p[4] = { f2bf(acc[m][n][0]), f2bf(acc[m][n][1]),
                              f2bf(acc[m][n][2]), f2bf(acc[m][n][3]) };
      if (sector == 2){
#pragma unroll
        for (int q = 0; q < 4; ++q) xwrT[(long)(nc + q) * 8192 + i] = p[q];
      } else {
        unsigned short* dst = sector == 0 ? xm : (sector == 1 ? xn : xl);
        *(uint2*)(dst + (long)i * 256 + nc) = *(const uint2*)p;
      }
    }
  }
}

// ---------- row norms of xm / xn ----------
__global__ __launch_bounds__(256) void k_norms(const unsigned short* xm, const unsigned short* xn,
                                               float* nm, float* nn){
  int w = threadIdx.x >> 6, lane = threadIdx.x & 63;
  int row = blockIdx.x * 4 + w;               // 0 .. 16384
  const unsigned short* src = (row < 8192) ? xm : xn;
  int rr = row & 8191;
  unsigned short v[4];
  *(uint2*)v = *(const uint2*)(src + (long)rr * 256 + lane * 4);
  float s = 0.f;
#pragma unroll
  for (int t = 0; t < 4; ++t){ float f = bf2f(v[t]); s += f * f; }
#pragma unroll
  for (int o = 32; o; o >>= 1) s += __shfl_xor(s, o);
  if (lane == 0) ((row < 8192) ? nm : nn)[rr] = s;
}

// ---------- pass B1: adj = f(xm @ xn^T)  (M=N=8192, K=256) ----------
// Epilogue round-trips the 128x128 f32 tile through LDS so global stores are
// full 128B lines per instruction (8 lanes x 16B contiguous per row).
template<bool WRITE_BF>
__global__ __launch_bounds__(256, 4) void k_adj(const unsigned short* xm, const unsigned short* xn,
    const float* nm, const float* nn, float* adj, unsigned short* adjbf){
  __shared__ char smem[32768];
  unsigned short* ldsA = (unsigned short*)smem;           // 16 KB
  unsigned short* ldsB = (unsigned short*)(smem + 16384); // 16 KB
  f32x4* ldsOut = (f32x4*)smem;                           // 32 KB [64 rows][32 slots]

  int tid = threadIdx.x, lane = tid & 63, w = tid >> 6;
  int r = lane & 15, gq = lane >> 4;
  int wi = w >> 1, wj = w & 1;
  int swz = xcd_swz(blockIdx.x, 4096);
  int bm = swz & 63, bn = swz >> 6;           // 64 x 64

  f32x4 acc1[4][4];
  f32x4 zero = {0.f, 0.f, 0.f, 0.f};
#pragma unroll
  for (int m = 0; m < 4; ++m)
#pragma unroll
    for (int n = 0; n < 4; ++n) acc1[m][n] = zero;

  for (int k0 = 0; k0 < 256; k0 += 64){
    __syncthreads();
    stage_async<128, 256>(ldsA, xm, (long)bm * 128, 256, k0, tid);
    stage_async<128, 256>(ldsB, xn, (long)bn * 128, 256, k0, tid);
    __syncthreads();
#pragma unroll
    for (int ks = 0; ks < 2; ++ks){
      int bb = ks * 64 + gq * 16;
      bf16x8 a[4], b[4];
#pragma unroll
      for (int m = 0; m < 4; ++m)
        a[m] = *(const bf16x8*)((const char*)ldsA + lds_off(wi * 64 + m * 16 + r, bb));
#pragma unroll
      for (int n = 0; n < 4; ++n)
        b[n] = *(const bf16x8*)((const char*)ldsB + lds_off(wj * 64 + n * 16 + r, bb));
      // swapped: row-dim (gq*4+q) = xn index j, col-dim (r) = xm index i
#pragma unroll
      for (int m = 0; m < 4; ++m)
#pragma unroll
        for (int n = 0; n < 4; ++n)
          acc1[m][n] = __builtin_amdgcn_mfma_f32_16x16x32_bf16(b[n], a[m], acc1[m][n], 0, 0, 0);
    }
  }

  // epilogue math in-place: acc1 <- adj values
  float nmi[4];
#pragma unroll
  for (int m = 0; m < 4; ++m) nmi[m] = nm[bm * 128 + wi * 64 + m * 16 + r];
#pragma unroll
  for (int n = 0; n < 4; ++n){
    int jb = bn * 128 + wj * 64 + n * 16 + gq * 4;
    float4 nn4 = *(const float4*)(nn + jb);
    const float nnq[4] = { nn4.x, nn4.y, nn4.z, nn4.w };
#pragma unroll
    for (int m = 0; m < 4; ++m){
      int i = bm * 128 + wi * 64 + m * 16 + r;
#pragma unroll
      for (int q = 0; q < 4; ++q){
        float sq = nmi[m] + nnq[q] - 2.f * acc1[m][n][q];
        float d = sqrtf(fmaxf(sq, 0.f)) * 0.5f;
        acc1[m][n][q] = (i == jb + q) ? 1.f : __expf(-d) * (1.f / 128.f);
      }
    }
  }

  // two 64-row passes through LDS -> fully coalesced global stores
#pragma unroll
  for (int p = 0; p < 2; ++p){
    __syncthreads();   // smem free of previous readers
    if (wi == p){
#pragma unroll
      for (int m = 0; m < 4; ++m){
        int row64 = m * 16 + r;
#pragma unroll
        for (int n = 0; n < 4; ++n){
          int slot = wj * 16 + n * 4 + gq;
          ldsOut[row64 * 32 + (slot ^ (row64 & 7))] = acc1[m][n];
        }
      }
    }
    __syncthreads();
    // read back: 256 threads cover 64 rows x 32 slots; per instr: 8 lanes x 16B
    // contiguous on one row = full 128B line.
#pragma unroll
    for (int c = 0; c < 8; ++c){
      int rr = w * 16 + ((lane >> 3) << 1) + (c & 1);
      int slot = (c >> 1) * 8 + (lane & 7);
      f32x4 v = ldsOut[rr * 32 + (slot ^ (rr & 7))];
      long grow = (long)(bm * 128 + p * 64 + rr) * 8192 + bn * 128 + slot * 4;
      *(f32x4*)(adj + grow) = v;
      if (WRITE_BF){
        unsigned short pb[4] = { f2bf(v[0]), f2bf(v[1]), f2bf(v[2]), f2bf(v[3]) };
        *(uint2*)(adjbf + grow) = *(const uint2*)pb;
      }
    }
  }
}

// ---------- pass B2: partial = adj @ xwr  (M=8192, K split, N=256) ----------
template<bool ABF>
__global__ __launch_bounds__(512, 2) void k_xr(const float* adj, const unsigned short* adjbf,
    const unsigned short* xwrT, float* partial, int klen, int nblk){
  __shared__ unsigned short ldsA[128 * 64];
  __shared__ unsigned short ldsB[256 * 64];
  int tid = threadIdx.x, lane = tid & 63, w = tid >> 6;
  int r = lane & 15, gq = lane >> 4;
  int wi = w >> 2, wc = w & 3;                // 2 x 4 -> 128 x 256
  int swz = xcd_swz(blockIdx.x, nblk);
  int bm = swz & 63, sp = swz >> 6;
  long j0 = (long)sp * klen;

  f32x4 acc[4][4];
  f32x4 zero = {0.f, 0.f, 0.f, 0.f};
#pragma unroll
  for (int m = 0; m < 4; ++m)
#pragma unroll
    for (int n = 0; n < 4; ++n) acc[m][n] = zero;

  for (int k0 = 0; k0 < klen; k0 += 64){
    __syncthreads();
    if (ABF) stage_async<128, 512>(ldsA, adjbf, (long)bm * 128, 8192, j0 + k0, tid);
    else     stage_f32  <128, 512>(ldsA, adj,   (long)bm * 128, 8192, j0 + k0, tid);
    stage_async<256, 512>(ldsB, xwrT, 0, 8192, j0 + k0, tid);
    __syncthreads();
#pragma unroll
    for (int ks = 0; ks < 2; ++ks){
      int bb = ks * 64 + gq * 16;
      bf16x8 a[4], b[4];
#pragma unroll
      for (int m = 0; m < 4; ++m)
        a[m] = *(const bf16x8*)((const char*)ldsA + lds_off(wi * 64 + m * 16 + r, bb));
#pragma unroll
      for (int n = 0; n < 4; ++n)
        b[n] = *(const bf16x8*)((const char*)ldsB + lds_off(wc * 64 + n * 16 + r, bb));
      // swapped: row-dim = xwrT index c, col-dim = adj row i
#pragma unroll
      for (int m = 0; m < 4; ++m)
#pragma unroll
        for (int n = 0; n < 4; ++n)
          acc[m][n] = __builtin_amdgcn_mfma_f32_16x16x32_bf16(b[n], a[m], acc[m][n], 0, 0, 0);
    }
  }
  float* dst = partial + (long)sp * 8192 * 256;
#pragma unroll
  for (int m = 0; m < 4; ++m){
    int i = bm * 128 + wi * 64 + m * 16 + r;
#pragma unroll
    for (int n = 0; n < 4; ++n){
      int cb = wc * 64 + n * 16 + gq * 4;
      *(f32x4*)(dst + (long)i * 256 + cb) = acc[m][n];
    }
  }
}

// ---------- reduce split partials -> xr (bf16) ----------
__global__ __launch_bounds__(256) void k_reduce_xr(const float* partial, unsigned short* xr, int S){
  long idx = ((long)blockIdx.x * 256 + threadIdx.x) * 4;
  float4 a = *(const float4*)(partial + idx);
  for (int s = 1; s < S; ++s){
    const float4 b = *(const float4*)(partial + (long)s * 8192 * 256 + idx);
    a.x += b.x; a.y += b.y; a.z += b.z; a.w += b.w;
  }
  unsigned short p[4] = { f2bf(a.x), f2bf(a.y), f2bf(a.z), f2bf(a.w) };
  *(uint2*)(xr + idx) = make_uint2((unsigned)p[0] | ((unsigned)p[1] << 16),
                                   (unsigned)p[2] | ((unsigned)p[3] << 16));
}

// ---------- pass C: w = sigmoid([xr|xl]@[Wrg;Wlg] + b), feat, score ----------
__global__ __launch_bounds__(512, 2) void k_gate(const unsigned short* xr, const unsigned short* xl,
    const unsigned short* WcatT, const float* brg, const float* blg,
    const float* Wp, float* score){
  __shared__ unsigned short ldsA[128 * 64];
  __shared__ unsigned short ldsB[256 * 64];
  int tid = threadIdx.x, lane = tid & 63, w = tid >> 6;
  int r = lane & 15, gq = lane >> 4;
  int wi = w >> 2, wc = w & 3;                // 2 x 4 -> 128 x 256
  int bm = blockIdx.x;

  f32x4 acc[4][4];
  f32x4 zero = {0.f, 0.f, 0.f, 0.f};
#pragma unroll
  for (int m = 0; m < 4; ++m)
#pragma unroll
    for (int n = 0; n < 4; ++n) acc[m][n] = zero;

  for (int k0 = 0; k0 < 512; k0 += 64){
    const unsigned short* A = (k0 < 256) ? xr : xl;
    __syncthreads();
    stage_async<128, 512>(ldsA, A, (long)bm * 128, 256, k0 & 255, tid);
    stage_async<256, 512>(ldsB, WcatT, 0, 512, k0, tid);
    __syncthreads();
#pragma unroll
    for (int ks = 0; ks < 2; ++ks){
      int bb = ks * 64 + gq * 16;
      bf16x8 a[4], b[4];
#pragma unroll
      for (int m = 0; m < 4; ++m)
        a[m] = *(const bf16x8*)((const char*)ldsA + lds_off(wi * 64 + m * 16 + r, bb));
#pragma unroll
      for (int n = 0; n < 4; ++n)
        b[n] = *(const bf16x8*)((const char*)ldsB + lds_off(wc * 64 + n * 16 + r, bb));
#pragma unroll
      for (int m = 0; m < 4; ++m)
#pragma unroll
        for (int n = 0; n < 4; ++n)
          acc[m][n] = __builtin_amdgcn_mfma_f32_16x16x32_bf16(b[n], a[m], acc[m][n], 0, 0, 0);
    }
  }
#pragma unroll
  for (int m = 0; m < 4; ++m){
    int i = bm * 128 + wi * 64 + m * 16 + r;
    float part = 0.f;
#pragma unroll
    for (int n = 0; n < 4; ++n){
      int cb = wc * 64 + n * 16 + gq * 4;
      float4 b4  = *(const float4*)(brg + cb);
      float4 l4  = *(const float4*)(blg + cb);
      float4 wp4 = *(const float4*)(Wp + cb);
      unsigned short xr4[4], xl4[4];
      *(uint2*)xr4 = *(const uint2*)(xr + (long)i * 256 + cb);
      *(uint2*)xl4 = *(const uint2*)(xl + (long)i * 256 + cb);
      const float bq[4] = { b4.x, b4.y, b4.z, b4.w };
      const float lq[4] = { l4.x, l4.y, l4.z, l4.w };
      const float pq[4] = { wp4.x, wp4.y, wp4.z, wp4.w };
#pragma unroll
      for (int q = 0; q < 4; ++q){
        float arg = acc[m][n][q] + bq[q] + lq[q];
        float wv = 1.f / (1.f + __expf(-arg));
        float feat = (1.f - wv) * bf2f(xr4[q]) + wv * bf2f(xl4[q]);
        part += feat * pq[q];
      }
    }
    part += __shfl_xor(part, 16);
    part += __shfl_xor(part, 32);
    if (gq == 0) atomicAdd(score + i, part);
  }
}

// ---------- host ----------
extern "C" void kernel_launch(void* const* d_in, const int* in_sizes, int n_in,
                              void* d_out, int out_size, void* d_ws, size_t ws_size,
                              hipStream_t stream){
  const float* x   = (const float*)d_in[0];
  const float* Wm  = (const float*)d_in[1];
  const float* Wn  = (const float*)d_in[2];
  const float* Wr  = (const float*)d_in[3];
  const float* Wt  = (const float*)d_in[4];
  const float* Wrg = (const float*)d_in[5];
  const float* brg = (const float*)d_in[6];
  const float* Wlg = (const float*)d_in[7];
  const float* blg = (const float*)d_in[8];
  const float* Wp  = (const float*)d_in[9];
  const float* bp  = (const float*)d_in[10];

  float* adj   = (float*)d_out;
  float* score = adj + 8192L * 8192;

  char* wsb = (char*)d_ws;
  unsigned short* xm    = (unsigned short*)(wsb);                 // 4 MB
  unsigned short* xn    = (unsigned short*)(wsb + (4L  << 20));   // 4 MB
  unsigned short* xwrT  = (unsigned short*)(wsb + (8L  << 20));   // 4 MB [256][8192]
  unsigned short* xl    = (unsigned short*)(wsb + (12L << 20));   // 4 MB
  unsigned short* xr    = (unsigned short*)(wsb + (16L << 20));   // 4 MB
  float*          nm    = (float*)         (wsb + (20L << 20));   // 32 KB
  float*          nn    = nm + 8192;                              // 32 KB
  unsigned short* WT    = (unsigned short*)(wsb + (21L << 20));   // 1 MB [1024][512]
  unsigned short* WcatT = (unsigned short*)(wsb + (22L << 20));   // 256 KB [256][512]
  unsigned short* xbf   = (unsigned short*)(wsb + (23L << 20));   // 8 MB [8192][512]
  float*          partial = (float*)(wsb + (31L << 20));          // NS * 8 MB

  int NS = 1;
  size_t base = 31L << 20;
  if      (ws_size >= base + 4 * (8L << 20)) NS = 4;
  else if (ws_size >= base + 2 * (8L << 20)) NS = 2;
  size_t adjbf_off = base + (size_t)NS * (8L << 20);
  bool use_bf = ws_size >= adjbf_off + (128L << 20);
  unsigned short* adjbf = (unsigned short*)(wsb + adjbf_off);

  k_prep  <<<2048, 256, 0, stream>>>(x, Wm, Wn, Wr, Wt, Wrg, Wlg, bp, WT, WcatT, xbf, score);
  k_gemmA <<<512, 256, 0, stream>>>(xbf, WT, xm, xn, xwrT, xl);
  k_norms <<<4096, 256, 0, stream>>>(xm, xn, nm, nn);
  if (use_bf){
    k_adj<true>  <<<4096, 256, 0, stream>>>(xm, xn, nm, nn, adj, adjbf);
    k_xr<true>   <<<64 * NS, 512, 0, stream>>>(adj, adjbf, xwrT, partial, 8192 / NS, 64 * NS);
  } else {
    k_adj<false> <<<4096, 256, 0, stream>>>(xm, xn, nm, nn, adj, adjbf);
    k_xr<false>  <<<64 * NS, 512, 0, stream>>>(adj, adjbf, xwrT, partial, 8192 / NS, 64 * NS);
  }
  k_reduce_xr<<<2048, 256, 0, stream>>>(partial, xr, NS);
  k_gate  <<<64, 512, 0, stream>>>(xr, xl, WcatT, brg, blg, Wp, score);
}

// Round 5
// 307.281 us; speedup vs baseline: 1.2301x; 1.1052x over previous
//
#include <hip/hip_runtime.h>
#include <stdint.h>

// ---------- types / helpers ----------
typedef __attribute__((ext_vector_type(8))) short bf16x8;
typedef __attribute__((ext_vector_type(4))) float f32x4;

__device__ __forceinline__ unsigned short f2bf(float f){
  unsigned u = __float_as_uint(f);
  u += 0x7FFFu + ((u >> 16) & 1u);          // round-to-nearest-even
  return (unsigned short)(u >> 16);
}
__device__ __forceinline__ float bf2f(unsigned short s){
  return __uint_as_float(((unsigned)s) << 16);
}

// LDS tile layout: [rows][64 bf16] = 128 B/row; 16B slot s of row r holds
// global slot (s ^ (r&7)).  Reads use lds_off; async writes are linear with
// pre-swizzled global source (global_load_lds requires linear LDS dest).
__device__ __forceinline__ int lds_off(int r, int b){
  return r * 128 + (b ^ ((r & 7) << 4));
}

__device__ __forceinline__ void cp16(const unsigned short* g, unsigned short* l){
  __builtin_amdgcn_global_load_lds(
      (const __attribute__((address_space(1))) unsigned int*)g,
      (__attribute__((address_space(3))) unsigned int*)l, 16, 0, 0);
}

// async stage: ROWS x 64 bf16 tile from rows of g at (row0, k0), swizzled source
template<int ROWS, int NT>
__device__ __forceinline__ void stage_async(unsigned short* lds, const unsigned short* g,
                                            long row0, long stride, long k0, int tid){
#pragma unroll
  for (int c = tid; c < ROWS * 8; c += NT){
    int r = c >> 3, s = c & 7;
    int ss = s ^ (r & 7);
    cp16(g + (row0 + r) * stride + k0 + ss * 8, lds + (long)(c & ~63) * 8);
  }
}

// register-path stage from f32 global rows (nontemporal), converting to bf16
template<int ROWS, int NT>
__device__ __forceinline__ void stage_f32_nt(unsigned short* lds, const float* g,
                                             long row0, long stride, long k0, int tid){
#pragma unroll
  for (int c = tid; c < ROWS * 8; c += NT){
    int r = c >> 3, s = c & 7;
    const f32x4* src = (const f32x4*)(g + (row0 + r) * stride + k0 + s * 8);
    f32x4 v0 = __builtin_nontemporal_load(src);
    f32x4 v1 = __builtin_nontemporal_load(src + 1);
    unsigned short t[8] = { f2bf(v0[0]), f2bf(v0[1]), f2bf(v0[2]), f2bf(v0[3]),
                            f2bf(v1[0]), f2bf(v1[1]), f2bf(v1[2]), f2bf(v1[3]) };
    *(uint4*)((char*)lds + lds_off(r, s * 16)) = *(const uint4*)t;
  }
}

// XCD-aware bijective swizzle (nwg % 8 == 0 in all uses)
__device__ __forceinline__ int xcd_swz(int bid, int nwg){
  int q = nwg >> 3;
  return (bid & 7) * q + (bid >> 3);
}

// ---------- prep: weights -> bf16 transposed, x -> bf16, init score ----------
__global__ __launch_bounds__(256) void k_prep(const float* x, const float* Wm, const float* Wn,
    const float* Wr, const float* Wt, const float* Wrg, const float* Wlg, const float* bp,
    unsigned short* WT, unsigned short* WcatT, unsigned short* xbf, float* score){
  long id = (long)blockIdx.x * 256 + threadIdx.x;   // 0 .. 524288
  if (id < 1024L * 512){
    int n = (int)(id >> 9), k = (int)(id & 511);
    const float* W = (n < 256) ? Wm : ((n < 512) ? Wn : ((n < 768) ? Wr : Wt));
    WT[id] = f2bf(W[(long)k * 256 + (n & 255)]);
  }
  if (id < 256L * 512){
    int n = (int)(id >> 9), k = (int)(id & 511);
    WcatT[id] = f2bf(k < 256 ? Wrg[(long)k * 256 + n] : Wlg[(long)(k - 256) * 256 + n]);
  }
  if (id < 8192) score[id] = bp[0];
  // x -> bf16 (8 per thread, 4M total)
  long xe = id * 8;
  float4 v0 = *(const float4*)(x + xe);
  float4 v1 = *(const float4*)(x + xe + 4);
  unsigned short t[8] = { f2bf(v0.x), f2bf(v0.y), f2bf(v0.z), f2bf(v0.w),
                          f2bf(v1.x), f2bf(v1.y), f2bf(v1.z), f2bf(v1.w) };
  *(uint4*)(xbf + xe) = *(const uint4*)t;
}

// ---------- pass A: [xm|xn|xwr|xl] = x @ [Wm|Wn|Wr|Wt]  (M=8192,K=512,N=1024) ----------
__global__ __launch_bounds__(256, 3) void k_gemmA(const unsigned short* xbf, const unsigned short* WT,
    unsigned short* xm, unsigned short* xn, unsigned short* xwrT, unsigned short* xl){
  __shared__ unsigned short ldsA[128 * 64];
  __shared__ unsigned short ldsB[128 * 64];
  int tid = threadIdx.x, lane = tid & 63, w = tid >> 6;
  int r = lane & 15, gq = lane >> 4;
  int wi = w >> 1, wc = w & 1;
  int swz = xcd_swz(blockIdx.x, 512);
  int bm = swz & 63, bn = swz >> 6;           // 64 x 8

  f32x4 acc[4][4];
  f32x4 zero = {0.f, 0.f, 0.f, 0.f};
#pragma unroll
  for (int m = 0; m < 4; ++m)
#pragma unroll
    for (int n = 0; n < 4; ++n) acc[m][n] = zero;

  for (int k0 = 0; k0 < 512; k0 += 64){
    __syncthreads();
    stage_async<128, 256>(ldsA, xbf, (long)bm * 128, 512, k0, tid);
    stage_async<128, 256>(ldsB, WT, (long)bn * 128, 512, k0, tid);
    __syncthreads();
#pragma unroll
    for (int ks = 0; ks < 2; ++ks){
      int bb = ks * 64 + gq * 16;
      bf16x8 a[4], b[4];
#pragma unroll
      for (int m = 0; m < 4; ++m)
        a[m] = *(const bf16x8*)((const char*)ldsA + lds_off(wi * 64 + m * 16 + r, bb));
#pragma unroll
      for (int n = 0; n < 4; ++n)
        b[n] = *(const bf16x8*)((const char*)ldsB + lds_off(wc * 64 + n * 16 + r, bb));
      // swapped: row-dim = WT index (n), col-dim = x row (i)
#pragma unroll
      for (int m = 0; m < 4; ++m)
#pragma unroll
        for (int n = 0; n < 4; ++n)
          acc[m][n] = __builtin_amdgcn_mfma_f32_16x16x32_bf16(b[n], a[m], acc[m][n], 0, 0, 0);
    }
  }
#pragma unroll
  for (int m = 0; m < 4; ++m){
    int i = bm * 128 + wi * 64 + m * 16 + r;
#pragma unroll
    for (int n = 0; n < 4; ++n){
      int ng = bn * 128 + wc * 64 + n * 16 + gq * 4;
      int sector = ng >> 8, nc = ng & 255;
      unsigned short p[4] = { f2bf(acc[m][n][0]), f2bf(acc[m][n][1]),
                              f2bf(acc[m][n][2]), f2bf(acc[m][n][3]) };
      if (sector == 2){
#pragma unroll
        for (int q = 0; q < 4; ++q) xwrT[(long)(nc + q) * 8192 + i] = p[q];
      } else {
        unsigned short* dst = sector == 0 ? xm : (sector == 1 ? xn : xl);
        *(uint2*)(dst + (long)i * 256 + nc) = *(const uint2*)p;
      }
    }
  }
}

// ---------- row norms of xm / xn ----------
__global__ __launch_bounds__(256) void k_norms(const unsigned short* xm, const unsigned short* xn,
                                               float* nm, float* nn){
  int w = threadIdx.x >> 6, lane = threadIdx.x & 63;
  int row = blockIdx.x * 4 + w;               // 0 .. 16384
  const unsigned short* src = (row < 8192) ? xm : xn;
  int rr = row & 8191;
  unsigned short v[4];
  *(uint2*)v = *(const uint2*)(src + (long)rr * 256 + lane * 4);
  float s = 0.f;
#pragma unroll
  for (int t = 0; t < 4; ++t){ float f = bf2f(v[t]); s += f * f; }
#pragma unroll
  for (int o = 32; o; o >>= 1) s += __shfl_xor(s, o);
  if (lane == 0) ((row < 8192) ? nm : nn)[rr] = s;
}

// ---------- pass B1: adj = f(xm @ xn^T)  (M=N=8192, K=256) ----------
// Epilogue round-trips the 128x128 f32 tile through LDS so global stores are
// full 128B lines per instruction, then streams them out nontemporally.
__global__ __launch_bounds__(256, 4) void k_adj(const unsigned short* xm, const unsigned short* xn,
    const float* nm, const float* nn, float* adj){
  __shared__ char smem[32768];
  unsigned short* ldsA = (unsigned short*)smem;           // 16 KB
  unsigned short* ldsB = (unsigned short*)(smem + 16384); // 16 KB
  f32x4* ldsOut = (f32x4*)smem;                           // 32 KB [64 rows][32 slots]

  int tid = threadIdx.x, lane = tid & 63, w = tid >> 6;
  int r = lane & 15, gq = lane >> 4;
  int wi = w >> 1, wj = w & 1;
  int swz = xcd_swz(blockIdx.x, 4096);
  int bm = swz & 63, bn = swz >> 6;           // 64 x 64

  f32x4 acc1[4][4];
  f32x4 zero = {0.f, 0.f, 0.f, 0.f};
#pragma unroll
  for (int m = 0; m < 4; ++m)
#pragma unroll
    for (int n = 0; n < 4; ++n) acc1[m][n] = zero;

  for (int k0 = 0; k0 < 256; k0 += 64){
    __syncthreads();
    stage_async<128, 256>(ldsA, xm, (long)bm * 128, 256, k0, tid);
    stage_async<128, 256>(ldsB, xn, (long)bn * 128, 256, k0, tid);
    __syncthreads();
#pragma unroll
    for (int ks = 0; ks < 2; ++ks){
      int bb = ks * 64 + gq * 16;
      bf16x8 a[4], b[4];
#pragma unroll
      for (int m = 0; m < 4; ++m)
        a[m] = *(const bf16x8*)((const char*)ldsA + lds_off(wi * 64 + m * 16 + r, bb));
#pragma unroll
      for (int n = 0; n < 4; ++n)
        b[n] = *(const bf16x8*)((const char*)ldsB + lds_off(wj * 64 + n * 16 + r, bb));
      // swapped: row-dim (gq*4+q) = xn index j, col-dim (r) = xm index i
#pragma unroll
      for (int m = 0; m < 4; ++m)
#pragma unroll
        for (int n = 0; n < 4; ++n)
          acc1[m][n] = __builtin_amdgcn_mfma_f32_16x16x32_bf16(b[n], a[m], acc1[m][n], 0, 0, 0);
    }
  }

  // epilogue math in-place: acc1 <- adj values
  float nmi[4];
#pragma unroll
  for (int m = 0; m < 4; ++m) nmi[m] = nm[bm * 128 + wi * 64 + m * 16 + r];
#pragma unroll
  for (int n = 0; n < 4; ++n){
    int jb = bn * 128 + wj * 64 + n * 16 + gq * 4;
    float4 nn4 = *(const float4*)(nn + jb);
    const float nnq[4] = { nn4.x, nn4.y, nn4.z, nn4.w };
#pragma unroll
    for (int m = 0; m < 4; ++m){
      int i = bm * 128 + wi * 64 + m * 16 + r;
#pragma unroll
      for (int q = 0; q < 4; ++q){
        float sq = nmi[m] + nnq[q] - 2.f * acc1[m][n][q];
        float d = sqrtf(fmaxf(sq, 0.f)) * 0.5f;
        acc1[m][n][q] = (i == jb + q) ? 1.f : __expf(-d) * (1.f / 128.f);
      }
    }
  }

  // two 64-row passes through LDS -> full-line nontemporal global stores
#pragma unroll
  for (int p = 0; p < 2; ++p){
    __syncthreads();   // smem free of previous readers
    if (wi == p){
#pragma unroll
      for (int m = 0; m < 4; ++m){
        int row64 = m * 16 + r;
#pragma unroll
        for (int n = 0; n < 4; ++n){
          int slot = wj * 16 + n * 4 + gq;
          ldsOut[row64 * 32 + (slot ^ (row64 & 7))] = acc1[m][n];
        }
      }
    }
    __syncthreads();
    // read back: 256 threads cover 64 rows x 32 slots; per instr: 8 lanes x 16B
    // contiguous on one row = full 128B line.
#pragma unroll
    for (int c = 0; c < 8; ++c){
      int rr = w * 16 + ((lane >> 3) << 1) + (c & 1);
      int slot = (c >> 1) * 8 + (lane & 7);
      f32x4 v = ldsOut[rr * 32 + (slot ^ (rr & 7))];
      long grow = (long)(bm * 128 + p * 64 + rr) * 8192 + bn * 128 + slot * 4;
      __builtin_nontemporal_store(v, (f32x4*)(adj + grow));
    }
  }
}

// ---------- pass B2: partial = adj @ xwr  (M=8192, K split, N=256) ----------
__global__ __launch_bounds__(512, 2) void k_xr(const float* adj,
    const unsigned short* xwrT, float* partial, int klen, int nblk){
  __shared__ unsigned short ldsA[128 * 64];
  __shared__ unsigned short ldsB[256 * 64];
  int tid = threadIdx.x, lane = tid & 63, w = tid >> 6;
  int r = lane & 15, gq = lane >> 4;
  int wi = w >> 2, wc = w & 3;                // 2 x 4 -> 128 x 256
  int swz = xcd_swz(blockIdx.x, nblk);
  int bm = swz & 63, sp = swz >> 6;           // sp == XCD id -> per-XCD K stripe
  long j0 = (long)sp * klen;

  f32x4 acc[4][4];
  f32x4 zero = {0.f, 0.f, 0.f, 0.f};
#pragma unroll
  for (int m = 0; m < 4; ++m)
#pragma unroll
    for (int n = 0; n < 4; ++n) acc[m][n] = zero;

  for (int k0 = 0; k0 < klen; k0 += 64){
    __syncthreads();
    stage_f32_nt<128, 512>(ldsA, adj, (long)bm * 128, 8192, j0 + k0, tid);
    stage_async<256, 512>(ldsB, xwrT, 0, 8192, j0 + k0, tid);
    __syncthreads();
#pragma unroll
    for (int ks = 0; ks < 2; ++ks){
      int bb = ks * 64 + gq * 16;
      bf16x8 a[4], b[4];
#pragma unroll
      for (int m = 0; m < 4; ++m)
        a[m] = *(const bf16x8*)((const char*)ldsA + lds_off(wi * 64 + m * 16 + r, bb));
#pragma unroll
      for (int n = 0; n < 4; ++n)
        b[n] = *(const bf16x8*)((const char*)ldsB + lds_off(wc * 64 + n * 16 + r, bb));
      // swapped: row-dim = xwrT index c, col-dim = adj row i
#pragma unroll
      for (int m = 0; m < 4; ++m)
#pragma unroll
        for (int n = 0; n < 4; ++n)
          acc[m][n] = __builtin_amdgcn_mfma_f32_16x16x32_bf16(b[n], a[m], acc[m][n], 0, 0, 0);
    }
  }
  float* dst = partial + (long)sp * 8192 * 256;
#pragma unroll
  for (int m = 0; m < 4; ++m){
    int i = bm * 128 + wi * 64 + m * 16 + r;
#pragma unroll
    for (int n = 0; n < 4; ++n){
      int cb = wc * 64 + n * 16 + gq * 4;
      __builtin_nontemporal_store(acc[m][n], (f32x4*)(dst + (long)i * 256 + cb));
    }
  }
}

// ---------- reduce split partials -> xr (bf16) ----------
__global__ __launch_bounds__(256) void k_reduce_xr(const float* partial, unsigned short* xr, int S){
  long idx = ((long)blockIdx.x * 256 + threadIdx.x) * 4;
  f32x4 a = __builtin_nontemporal_load((const f32x4*)(partial + idx));
  for (int s = 1; s < S; ++s){
    f32x4 b = __builtin_nontemporal_load((const f32x4*)(partial + (long)s * 8192 * 256 + idx));
    a += b;
  }
  unsigned short p[4] = { f2bf(a[0]), f2bf(a[1]), f2bf(a[2]), f2bf(a[3]) };
  *(uint2*)(xr + idx) = make_uint2((unsigned)p[0] | ((unsigned)p[1] << 16),
                                   (unsigned)p[2] | ((unsigned)p[3] << 16));
}

// ---------- pass C: w = sigmoid([xr|xl]@[Wrg;Wlg] + b), feat, score ----------
__global__ __launch_bounds__(512, 2) void k_gate(const unsigned short* xr, const unsigned short* xl,
    const unsigned short* WcatT, const float* brg, const float* blg,
    const float* Wp, float* score){
  __shared__ unsigned short ldsA[128 * 64];
  __shared__ unsigned short ldsB[256 * 64];
  int tid = threadIdx.x, lane = tid & 63, w = tid >> 6;
  int r = lane & 15, gq = lane >> 4;
  int wi = w >> 2, wc = w & 3;                // 2 x 4 -> 128 x 256
  int bm = blockIdx.x;

  f32x4 acc[4][4];
  f32x4 zero = {0.f, 0.f, 0.f, 0.f};
#pragma unroll
  for (int m = 0; m < 4; ++m)
#pragma unroll
    for (int n = 0; n < 4; ++n) acc[m][n] = zero;

  for (int k0 = 0; k0 < 512; k0 += 64){
    const unsigned short* A = (k0 < 256) ? xr : xl;
    __syncthreads();
    stage_async<128, 512>(ldsA, A, (long)bm * 128, 256, k0 & 255, tid);
    stage_async<256, 512>(ldsB, WcatT, 0, 512, k0, tid);
    __syncthreads();
#pragma unroll
    for (int ks = 0; ks < 2; ++ks){
      int bb = ks * 64 + gq * 16;
      bf16x8 a[4], b[4];
#pragma unroll
      for (int m = 0; m < 4; ++m)
        a[m] = *(const bf16x8*)((const char*)ldsA + lds_off(wi * 64 + m * 16 + r, bb));
#pragma unroll
      for (int n = 0; n < 4; ++n)
        b[n] = *(const bf16x8*)((const char*)ldsB + lds_off(wc * 64 + n * 16 + r, bb));
#pragma unroll
      for (int m = 0; m < 4; ++m)
#pragma unroll
        for (int n = 0; n < 4; ++n)
          acc[m][n] = __builtin_amdgcn_mfma_f32_16x16x32_bf16(b[n], a[m], acc[m][n], 0, 0, 0);
    }
  }
#pragma unroll
  for (int m = 0; m < 4; ++m){
    int i = bm * 128 + wi * 64 + m * 16 + r;
    float part = 0.f;
#pragma unroll
    for (int n = 0; n < 4; ++n){
      int cb = wc * 64 + n * 16 + gq * 4;
      float4 b4  = *(const float4*)(brg + cb);
      float4 l4  = *(const float4*)(blg + cb);
      float4 wp4 = *(const float4*)(Wp + cb);
      unsigned short xr4[4], xl4[4];
      *(uint2*)xr4 = *(const uint2*)(xr + (long)i * 256 + cb);
      *(uint2*)xl4 = *(const uint2*)(xl + (long)i * 256 + cb);
      const float bq[4] = { b4.x, b4.y, b4.z, b4.w };
      const float lq[4] = { l4.x, l4.y, l4.z, l4.w };
      const float pq[4] = { wp4.x, wp4.y, wp4.z, wp4.w };
#pragma unroll
      for (int q = 0; q < 4; ++q){
        float arg = acc[m][n][q] + bq[q] + lq[q];
        float wv = 1.f / (1.f + __expf(-arg));
        float feat = (1.f - wv) * bf2f(xr4[q]) + wv * bf2f(xl4[q]);
        part += feat * pq[q];
      }
    }
    part += __shfl_xor(part, 16);
    part += __shfl_xor(part, 32);
    if (gq == 0) atomicAdd(score + i, part);
  }
}

// ---------- host ----------
extern "C" void kernel_launch(void* const* d_in, const int* in_sizes, int n_in,
                              void* d_out, int out_size, void* d_ws, size_t ws_size,
                              hipStream_t stream){
  const float* x   = (const float*)d_in[0];
  const float* Wm  = (const float*)d_in[1];
  const float* Wn  = (const float*)d_in[2];
  const float* Wr  = (const float*)d_in[3];
  const float* Wt  = (const float*)d_in[4];
  const float* Wrg = (const float*)d_in[5];
  const float* brg = (const float*)d_in[6];
  const float* Wlg = (const float*)d_in[7];
  const float* blg = (const float*)d_in[8];
  const float* Wp  = (const float*)d_in[9];
  const float* bp  = (const float*)d_in[10];

  float* adj   = (float*)d_out;
  float* score = adj + 8192L * 8192;

  char* wsb = (char*)d_ws;
  unsigned short* xm    = (unsigned short*)(wsb);                 // 4 MB
  unsigned short* xn    = (unsigned short*)(wsb + (4L  << 20));   // 4 MB
  unsigned short* xwrT  = (unsigned short*)(wsb + (8L  << 20));   // 4 MB [256][8192]
  unsigned short* xl    = (unsigned short*)(wsb + (12L << 20));   // 4 MB
  unsigned short* xr    = (unsigned short*)(wsb + (16L << 20));   // 4 MB
  float*          nm    = (float*)         (wsb + (20L << 20));   // 32 KB
  float*          nn    = nm + 8192;                              // 32 KB
  unsigned short* WT    = (unsigned short*)(wsb + (21L << 20));   // 1 MB [1024][512]
  unsigned short* WcatT = (unsigned short*)(wsb + (22L << 20));   // 256 KB [256][512]
  unsigned short* xbf   = (unsigned short*)(wsb + (23L << 20));   // 8 MB [8192][512]
  float*          partial = (float*)(wsb + (31L << 20));          // NS * 8 MB

  int NS = 1;
  size_t base = 31L << 20;
  if      (ws_size >= base + 8 * (8L << 20)) NS = 8;
  else if (ws_size >= base + 4 * (8L << 20)) NS = 4;
  else if (ws_size >= base + 2 * (8L << 20)) NS = 2;

  k_prep  <<<2048, 256, 0, stream>>>(x, Wm, Wn, Wr, Wt, Wrg, Wlg, bp, WT, WcatT, xbf, score);
  k_gemmA <<<512, 256, 0, stream>>>(xbf, WT, xm, xn, xwrT, xl);
  k_norms <<<4096, 256, 0, stream>>>(xm, xn, nm, nn);
  k_adj   <<<4096, 256, 0, stream>>>(xm, xn, nm, nn, adj);
  k_xr    <<<64 * NS, 512, 0, stream>>>(adj, xwrT, partial, 8192 / NS, 64 * NS);
  k_reduce_xr<<<2048, 256, 0, stream>>>(partial, xr, NS);
  k_gate  <<<64, 512, 0, stream>>>(xr, xl, WcatT, brg, blg, Wp, score);
}